// Round 11
// baseline (444.449 us; speedup 1.0000x reference)
//
#include <hip/hip_runtime.h>
#include <hip/hip_bf16.h>
#include <math.h>
#include <stdint.h>

#define NN 50000
#define NE 400000
#define NT 25000          // NE/16 edge tiles
#define NWAVES 2048       // 512 blocks x 4 waves

typedef __attribute__((ext_vector_type(8))) short short8;
typedef __attribute__((ext_vector_type(4))) float f32x4;

// bf16 weight workspace layout (element offsets)
#define OFF_W1S  0           // [128][128]  We1 rows 0..127   (src half), transposed
#define OFF_W1D  16384       // [128][128]  We1 rows 128..255 (dst half)
#define OFF_W1E  32768       // [128][64]   We1 rows 256..319 (edge_attr part)
#define OFF_WE2T 40960       // [128][128]
#define OFF_WN1T 57344       // [128][256]
#define OFF_WN2T 90112       // [128][128]
#define OFF_WC1T 106496      // [64][128]
#define W_TOTAL  114688

__device__ __forceinline__ float silu_f(float x) {
    return x * (1.0f / (1.0f + __expf(-x)));
}
__device__ __forceinline__ short f2bf(float f) {
    __hip_bfloat16 b = __float2bfloat16(f);
    return *reinterpret_cast<short*>(&b);
}
__device__ __forceinline__ float bf2f(short s) {
    uint32_t u = ((uint32_t)(uint16_t)s) << 16;
    float f; __builtin_memcpy(&f, &u, 4); return f;
}
__device__ __forceinline__ uint32_t pk2(float lo, float hi) {
    return (uint32_t)(uint16_t)f2bf(lo) | ((uint32_t)(uint16_t)f2bf(hi) << 16);
}
__device__ __forceinline__ short8 cvt8(float4 a, float4 b) {
    short8 r;
    r[0] = f2bf(a.x); r[1] = f2bf(a.y); r[2] = f2bf(a.z); r[3] = f2bf(a.w);
    r[4] = f2bf(b.x); r[5] = f2bf(b.y); r[6] = f2bf(b.z); r[7] = f2bf(b.w);
    return r;
}

// C-pack -> B-fragment lane exchange (proven R4/R5/R9/R10).
__device__ __forceinline__ short8 exch8(uint32_t e0, uint32_t e1,
                                        uint32_t o0, uint32_t o1,
                                        int g, int le) {
    const int srcA = le + 16 * ((g & 1) * 2);
    const int srcB = srcA + 16;
    const uint32_t a0e = __shfl((int)e0, srcA), a0o = __shfl((int)o0, srcA);
    const uint32_t a1e = __shfl((int)e1, srcA), a1o = __shfl((int)o1, srcA);
    const uint32_t b0e = __shfl((int)e0, srcB), b0o = __shfl((int)o0, srcB);
    const uint32_t b1e = __shfl((int)e1, srcB), b1o = __shfl((int)o1, srcB);
    const bool hi = (g & 2) != 0;
    uint32_t v[4];
    v[0] = hi ? a0o : a0e;  v[1] = hi ? a1o : a1e;
    v[2] = hi ? b0o : b0e;  v[3] = hi ? b1o : b1e;
    short8 r; __builtin_memcpy(&r, v, 16); return r;
}

// async global->LDS, 16B/lane; LDS dest = wave-uniform base + lane*16
__device__ __forceinline__ void gload16(const short* g, short* l) {
    __builtin_amdgcn_global_load_lds(
        (const __attribute__((address_space(1))) void*)g,
        (__attribute__((address_space(3))) void*)l, 16, 0, 0);
}

// ---------------- zero aggr/coord accumulators ----------------
__global__ void zero_kernel(float4* __restrict__ p, int n4) {
    int i = blockIdx.x * blockDim.x + threadIdx.x;
    int st = gridDim.x * blockDim.x;
    for (; i < n4; i += st) p[i] = make_float4(0.f, 0.f, 0.f, 0.f);
}

// ---------------- prep: weights fp32 [K][N] -> bf16 transposed [N][K] ----------------
__global__ __launch_bounds__(256) void prep_kernel(
    const float* __restrict__ We1, const float* __restrict__ We2,
    const float* __restrict__ Wn1, const float* __restrict__ Wn2,
    const float* __restrict__ Wc1, short* __restrict__ wb)
{
    const int i = blockIdx.x * 256 + threadIdx.x;
    if (i >= W_TOTAL) return;
    float v; int rel, n, k;
    if (i < OFF_W1D)       { rel = i;            n = rel >> 7; k = rel & 127; v = We1[k * 128 + n]; }
    else if (i < OFF_W1E)  { rel = i - OFF_W1D;  n = rel >> 7; k = rel & 127; v = We1[(k + 128) * 128 + n]; }
    else if (i < OFF_WE2T) { rel = i - OFF_W1E;  n = rel >> 6; k = rel & 63;  v = We1[(k + 256) * 128 + n]; }
    else if (i < OFF_WN1T) { rel = i - OFF_WE2T; n = rel >> 7; k = rel & 127; v = We2[k * 128 + n]; }
    else if (i < OFF_WN2T) { rel = i - OFF_WN1T; n = rel >> 8; k = rel & 255; v = Wn1[k * 128 + n]; }
    else if (i < OFF_WC1T) { rel = i - OFF_WN2T; n = rel >> 7; k = rel & 127; v = Wn2[k * 128 + n]; }
    else                   { rel = i - OFF_WC1T; n = rel >> 7; k = rel & 127; v = Wc1[k * 64 + n]; }
    wb[i] = f2bf(v);
}

// ---------------- ynode: Ys = nf @ We1_src, Yd = nf @ We1_dst (bf16 out) ----------------
__global__ __launch_bounds__(256, 4) void ynode_kernel(
    const float* __restrict__ nf, const short* __restrict__ wb,
    short* __restrict__ ysb, short* __restrict__ ydb)
{
    const int tid = threadIdx.x;
    const int wv = tid >> 6, lane = tid & 63, le = lane & 15, grp = lane >> 4;
    const int nb = blockIdx.x * 128, wbase = wv * 32;
    const int row0 = min(nb + wbase + le, NN - 1);
    const int row1 = min(nb + wbase + 16 + le, NN - 1);

    #pragma unroll 1
    for (int pass = 0; pass < 2; ++pass) {
        const short* wt = wb + (pass ? OFF_W1D : OFF_W1S);
        short* op = pass ? ydb : ysb;

        f32x4 acc[2][8];
        #pragma unroll
        for (int m = 0; m < 2; ++m)
            #pragma unroll
            for (int t = 0; t < 8; ++t) acc[m][t] = (f32x4){0.f, 0.f, 0.f, 0.f};

        #pragma unroll
        for (int kc = 0; kc < 4; ++kc) {
            const int gk = kc * 32 + grp * 8;
            const float* p0 = nf + (size_t)row0 * 128 + gk;
            const float* p1 = nf + (size_t)row1 * 128 + gk;
            const short8 a0 = cvt8(*(const float4*)p0, *(const float4*)(p0 + 4));
            const short8 a1 = cvt8(*(const float4*)p1, *(const float4*)(p1 + 4));
            short8 bfv[8];
            #pragma unroll
            for (int t = 0; t < 8; ++t)
                bfv[t] = *(const short8*)(wt + (size_t)(t * 16 + le) * 128 + gk);
            #pragma unroll
            for (int t = 0; t < 8; ++t) {
                acc[0][t] = __builtin_amdgcn_mfma_f32_16x16x32_bf16(a0, bfv[t], acc[0][t], 0, 0, 0);
                acc[1][t] = __builtin_amdgcn_mfma_f32_16x16x32_bf16(a1, bfv[t], acc[1][t], 0, 0, 0);
            }
        }
        #pragma unroll
        for (int t = 0; t < 8; ++t)
            #pragma unroll
            for (int m = 0; m < 2; ++m)
                #pragma unroll
                for (int r = 0; r < 4; ++r) {
                    const int row = nb + wbase + m * 16 + grp * 4 + r;
                    if (row < NN)
                        op[(size_t)row * 128 + t * 16 + le] = f2bf(acc[m][t][r]);
                }
    }
}

// ---------------- edge pipeline: multi-tile loop, double-buffered gload_lds ----------------
// 512 blocks x 4 waves; each wave loops ~12 tiles of 16 edges. Per iteration:
// issue next tile's gathers/ea/idx (exactly 14 VM ops), vmcnt(14) (free in
// steady state), compute current tile from registers + LDS. Weight fragments
// are loop-invariant -> held in registers across tiles (bounds(256,2)).
__global__ __launch_bounds__(256, 2) void edge_kernel(
    const short* __restrict__ ysb, const short* __restrict__ ydb,
    const float* __restrict__ ea, const float* __restrict__ coords,
    const int* __restrict__ ei, const short* __restrict__ wb,
    const float* __restrict__ be1, const float* __restrict__ be2,
    const float* __restrict__ bc1, const float* __restrict__ bc2,
    const float* __restrict__ Wc2f,
    float* __restrict__ aggr, float* __restrict__ coord_acc)
{
    __shared__ short smem[4][2][4096];   // per wave: 2 x 8KB stage buffers

    const int tid = threadIdx.x;
    const int wv = tid >> 6, lane = tid & 63, le = lane & 15, g = lane >> 4;
    const int t0 = blockIdx.x * 4 + wv;
    if (t0 >= NT) return;

    const short* w1e = wb + OFF_W1E;
    const short* w2  = wb + OFF_WE2T;
    const short* wc  = wb + OFF_WC1T;

    // ---- prologue: tile t0 ----
    int sc, dc, sn, dn;
    float4 ea_c[4], ea_n[4];
    {
        const int e0 = t0 * 16 + le;
        sc = ei[e0]; dc = ei[NE + e0];
        const float* pe = ea + (size_t)e0 * 64 + g * 8;
        ea_c[0] = *(const float4*)pe;        ea_c[1] = *(const float4*)(pe + 4);
        ea_c[2] = *(const float4*)(pe + 32); ea_c[3] = *(const float4*)(pe + 36);
    }
    #pragma unroll
    for (int cc = 0; cc < 4; ++cc) {
        gload16(ysb + (size_t)sc * 128 + cc * 32 + g * 8, &smem[wv][0][cc * 512]);
        gload16(ydb + (size_t)dc * 128 + cc * 32 + g * 8, &smem[wv][0][2048 + cc * 512]);
    }
    {
        const int t1 = (t0 + NWAVES < NT) ? t0 + NWAVES : t0;
        const int e1 = t1 * 16 + le;
        sn = ei[e1]; dn = ei[NE + e1];
    }

    int b = 0;
    #pragma unroll 1
    for (int t = t0; t < NT; t += NWAVES, b ^= 1) {
        short* bufc = smem[wv][b];
        short* bufn = smem[wv][b ^ 1];
        const int s0 = sc, d0 = dc;

        // ---- 1. prefetch next tile: 8 gload16 + 4 ea loads + 2 idx = 14 VM ops ----
        #pragma unroll
        for (int cc = 0; cc < 4; ++cc) {
            gload16(ysb + (size_t)sn * 128 + cc * 32 + g * 8, bufn + cc * 512);
            gload16(ydb + (size_t)dn * 128 + cc * 32 + g * 8, bufn + 2048 + cc * 512);
        }
        {
            const int tn = (t + NWAVES < NT) ? t + NWAVES : t;
            const float* pe = ea + (size_t)(tn * 16 + le) * 64 + g * 8;
            ea_n[0] = *(const float4*)pe;        ea_n[1] = *(const float4*)(pe + 4);
            ea_n[2] = *(const float4*)(pe + 32); ea_n[3] = *(const float4*)(pe + 36);
        }
        int sf, df;
        {
            const int t2 = (t + 2 * NWAVES < NT) ? t + 2 * NWAVES : t;
            const int e2 = t2 * 16 + le;
            sf = ei[e2]; df = ei[NE + e2];
        }

        // ---- 2. wait for CURRENT tile's gathers (issued a full iteration ago) ----
        __builtin_amdgcn_sched_barrier(0);
        asm volatile("s_waitcnt vmcnt(14)" ::: "memory");
        __builtin_amdgcn_sched_barrier(0);

        // ---- 3. MLP1 ea-part (swapped): C lane le = edge, col t*16+g*4+r ----
        f32x4 acc[8];
        #pragma unroll
        for (int q = 0; q < 8; ++q) acc[q] = (f32x4){0.f, 0.f, 0.f, 0.f};
        #pragma unroll
        for (int kc = 0; kc < 2; ++kc) {
            const short8 eaB = cvt8(ea_c[kc * 2], ea_c[kc * 2 + 1]);
            const int gk = kc * 32 + g * 8;
            short8 wfv[8];
            #pragma unroll
            for (int q = 0; q < 8; ++q)
                wfv[q] = *(const short8*)(w1e + (size_t)(q * 16 + le) * 64 + gk);
            #pragma unroll
            for (int q = 0; q < 8; ++q)
                acc[q] = __builtin_amdgcn_mfma_f32_16x16x32_bf16(wfv[q], eaB, acc[q], 0, 0, 0);
        }
        uint32_t hp[8][2];
        #pragma unroll
        for (int q = 0; q < 8; ++q) {
            hp[q][0] = pk2(acc[q][0], acc[q][1]);
            hp[q][1] = pk2(acc[q][2], acc[q][3]);
        }

        // ---- 4. h1 B-frags: exch(ea-part) + Ys + Yd + be1, silu ----
        short8 h1f[4];
        #pragma unroll
        for (int cc = 0; cc < 4; ++cc) {
            const short8 ys = *(const short8*)&bufc[cc * 512 + lane * 8];
            const short8 yd = *(const short8*)&bufc[2048 + cc * 512 + lane * 8];
            const short8 ex = exch8(hp[cc*2][0], hp[cc*2][1], hp[cc*2+1][0], hp[cc*2+1][1], g, le);
            const float* bp = be1 + cc * 32 + g * 8;
            #pragma unroll
            for (int j = 0; j < 8; ++j)
                h1f[cc][j] = f2bf(silu_f(bf2f(ex[j]) + bf2f(ys[j]) + bf2f(yd[j]) + bp[j]));
        }

        // ---- 5. MLP2 (swapped), K=128 ----
        f32x4 acc2[8];
        #pragma unroll
        for (int q = 0; q < 8; ++q) acc2[q] = (f32x4){0.f, 0.f, 0.f, 0.f};
        #pragma unroll
        for (int cc = 0; cc < 4; ++cc) {
            const int gk = cc * 32 + g * 8;
            short8 wfv[8];
            #pragma unroll
            for (int q = 0; q < 8; ++q)
                wfv[q] = *(const short8*)(w2 + (size_t)(q * 16 + le) * 128 + gk);
            #pragma unroll
            for (int q = 0; q < 8; ++q)
                acc2[q] = __builtin_amdgcn_mfma_f32_16x16x32_bf16(wfv[q], h1f[cc], acc2[q], 0, 0, 0);
        }

        // ---- 6. h2: bias+silu, bf16 packs, Ht tile into dead bufc region ----
        uint32_t hq[8][2];
        #pragma unroll
        for (int t8 = 0; t8 < 8; ++t8) {
            float hv[4];
            #pragma unroll
            for (int r = 0; r < 4; ++r) {
                const int col = t8 * 16 + g * 4 + r;
                hv[r] = silu_f(acc2[t8][r] + be2[col]);
            }
            hq[t8][0] = pk2(hv[0], hv[1]);
            hq[t8][1] = pk2(hv[2], hv[3]);
            #pragma unroll
            for (int r = 0; r < 4; ++r)
                bufc[le * 136 + t8 * 16 + g * 4 + r] = f2bf(hv[r]);
        }

        // ---- 7. quarter-wave contiguous atomic scatter (full 64B line / instr) ----
        #pragma unroll
        for (int r = 0; r < 4; ++r) {
            const int er = g * 4 + r;
            const int dr = __shfl(d0, er);
            #pragma unroll
            for (int t8 = 0; t8 < 8; ++t8) {
                const int t2 = (t8 + g) & 7;
                atomicAdd(&aggr[(size_t)dr * 128 + t2 * 16 + le],
                          bf2f(bufc[er * 136 + t2 * 16 + le]));
            }
        }

        // ---- 8. coord MLP (swapped), N=64, B-frags from exch8 ----
        short8 h2f[4];
        #pragma unroll
        for (int cc = 0; cc < 4; ++cc)
            h2f[cc] = exch8(hq[cc*2][0], hq[cc*2][1], hq[cc*2+1][0], hq[cc*2+1][1], g, le);

        f32x4 acc3[4];
        #pragma unroll
        for (int q = 0; q < 4; ++q) acc3[q] = (f32x4){0.f, 0.f, 0.f, 0.f};
        #pragma unroll
        for (int cc = 0; cc < 4; ++cc) {
            const int gk = cc * 32 + g * 8;
            short8 wfv[4];
            #pragma unroll
            for (int q = 0; q < 4; ++q)
                wfv[q] = *(const short8*)(wc + (size_t)(q * 16 + le) * 128 + gk);
            #pragma unroll
            for (int q = 0; q < 4; ++q)
                acc3[q] = __builtin_amdgcn_mfma_f32_16x16x32_bf16(wfv[q], h2f[cc], acc3[q], 0, 0, 0);
        }

        // ---- 9. coord_w reduce + geometry ----
        float part = 0.f;
        #pragma unroll
        for (int q = 0; q < 4; ++q)
            #pragma unroll
            for (int r = 0; r < 4; ++r) {
                const int col = q * 16 + g * 4 + r;
                part += silu_f(acc3[q][r] + bc1[col]) * Wc2f[col];
            }
        part += __shfl_xor(part, 16);
        part += __shfl_xor(part, 32);

        if (g == 0) {
            const float wq = part + bc2[0];
            const float dx = coords[3 * s0 + 0] - coords[3 * d0 + 0];
            const float dy = coords[3 * s0 + 1] - coords[3 * d0 + 1];
            const float dz = coords[3 * s0 + 2] - coords[3 * d0 + 2];
            const float inv = wq / (sqrtf(dx * dx + dy * dy + dz * dz) + 1e-8f);
            atomicAdd(&coord_acc[3 * d0 + 0], dx * inv);
            atomicAdd(&coord_acc[3 * d0 + 1], dy * inv);
            atomicAdd(&coord_acc[3 * d0 + 2], dz * inv);
        }

        // ---- 10. rotate pipeline registers ----
        sc = sn; dc = dn; sn = sf; dn = df;
        #pragma unroll
        for (int i = 0; i < 4; ++i) ea_c[i] = ea_n[i];
    }
}

// ---------------- node update (MFMA, barrier-free, fp32 inputs) ----------------
__global__ __launch_bounds__(256, 2) void node_kernel(
    const float* __restrict__ nf, const float* __restrict__ coords,
    const short* __restrict__ wb,
    const float* __restrict__ bn1, const float* __restrict__ bn2,
    const float* __restrict__ aggr, const float* __restrict__ coord_acc,
    float* __restrict__ out)
{
    __shared__ short Hs[128][136];

    const int tid = threadIdx.x;
    const int wv = tid >> 6, lane = tid & 63, le = lane & 15, grp = lane >> 4;
    const int nb = blockIdx.x * 128, wbase = wv * 32;
    const int row0 = min(nb + wbase + le, NN - 1);
    const int row1 = min(nb + wbase + 16 + le, NN - 1);

    f32x4 acc[2][8];
    #pragma unroll
    for (int m = 0; m < 2; ++m)
        #pragma unroll
        for (int t = 0; t < 8; ++t) acc[m][t] = (f32x4){0.f, 0.f, 0.f, 0.f};

    const short* w1 = wb + OFF_WN1T;
    #pragma unroll
    for (int kc = 0; kc < 8; ++kc) {
        const int gk = kc * 32 + grp * 8;
        const float* p0 = (kc < 4) ? nf + (size_t)row0 * 128 + gk : aggr + (size_t)row0 * 128 + gk - 128;
        const float* p1 = (kc < 4) ? nf + (size_t)row1 * 128 + gk : aggr + (size_t)row1 * 128 + gk - 128;
        const short8 a0 = cvt8(*(const float4*)p0, *(const float4*)(p0 + 4));
        const short8 a1 = cvt8(*(const float4*)p1, *(const float4*)(p1 + 4));
        short8 bfv[8];
        #pragma unroll
        for (int t = 0; t < 8; ++t)
            bfv[t] = *(const short8*)(w1 + (size_t)(t * 16 + le) * 256 + gk);
        #pragma unroll
        for (int t = 0; t < 8; ++t) {
            acc[0][t] = __builtin_amdgcn_mfma_f32_16x16x32_bf16(a0, bfv[t], acc[0][t], 0, 0, 0);
            acc[1][t] = __builtin_amdgcn_mfma_f32_16x16x32_bf16(a1, bfv[t], acc[1][t], 0, 0, 0);
        }
    }
    #pragma unroll
    for (int t = 0; t < 8; ++t) {
        const float b1 = bn1[t * 16 + le];
        #pragma unroll
        for (int m = 0; m < 2; ++m)
            #pragma unroll
            for (int r = 0; r < 4; ++r)
                Hs[wbase + m * 16 + grp * 4 + r][t * 16 + le] = f2bf(silu_f(acc[m][t][r] + b1));
    }

    f32x4 acc2[2][8];
    #pragma unroll
    for (int m = 0; m < 2; ++m)
        #pragma unroll
        for (int t = 0; t < 8; ++t) acc2[m][t] = (f32x4){0.f, 0.f, 0.f, 0.f};

    const short* w2 = wb + OFF_WN2T;
    #pragma unroll
    for (int kc = 0; kc < 4; ++kc) {
        const int gk = kc * 32 + grp * 8;
        const short8 a0 = *(const short8*)&Hs[wbase + le][gk];
        const short8 a1 = *(const short8*)&Hs[wbase + 16 + le][gk];
        short8 bfv[8];
        #pragma unroll
        for (int t = 0; t < 8; ++t)
            bfv[t] = *(const short8*)(w2 + (size_t)(t * 16 + le) * 128 + gk);
        #pragma unroll
        for (int t = 0; t < 8; ++t) {
            acc2[0][t] = __builtin_amdgcn_mfma_f32_16x16x32_bf16(a0, bfv[t], acc2[0][t], 0, 0, 0);
            acc2[1][t] = __builtin_amdgcn_mfma_f32_16x16x32_bf16(a1, bfv[t], acc2[1][t], 0, 0, 0);
        }
    }
    #pragma unroll
    for (int t = 0; t < 8; ++t) {
        const float b2 = bn2[t * 16 + le];
        #pragma unroll
        for (int m = 0; m < 2; ++m)
            #pragma unroll
            for (int r = 0; r < 4; ++r) {
                const int row = nb + wbase + m * 16 + grp * 4 + r;
                if (row < NN) {
                    const int c = t * 16 + le;
                    out[(size_t)row * 128 + c] = acc2[m][t][r] + b2 + nf[(size_t)row * 128 + c];
                }
            }
    }

    for (int i = tid; i < 384; i += 256) {
        const int n = nb + i / 3, j = i % 3;
        if (n < NN)
            out[(size_t)NN * 128 + 3 * n + j] = coords[3 * n + j] + coord_acc[3 * n + j];
    }
}

extern "C" void kernel_launch(void* const* d_in, const int* in_sizes, int n_in,
                              void* d_out, int out_size, void* d_ws, size_t ws_size,
                              hipStream_t stream)
{
    const float* node_feat  = (const float*)d_in[0];
    const float* edge_attr  = (const float*)d_in[1];
    const float* coords     = (const float*)d_in[2];
    const int*   edge_index = (const int*)d_in[3];
    const float* We1 = (const float*)d_in[4];
    const float* be1 = (const float*)d_in[5];
    const float* We2 = (const float*)d_in[6];
    const float* be2 = (const float*)d_in[7];
    const float* Wn1 = (const float*)d_in[8];
    const float* bn1 = (const float*)d_in[9];
    const float* Wn2 = (const float*)d_in[10];
    const float* bn2 = (const float*)d_in[11];
    const float* Wc1 = (const float*)d_in[12];
    const float* bc1 = (const float*)d_in[13];
    const float* Wc2 = (const float*)d_in[14];
    const float* bc2 = (const float*)d_in[15];
    float* out = (float*)d_out;

    const size_t sz_wb  = (size_t)W_TOTAL * 2;      // 229 KB
    const size_t sz_agg = (size_t)NN * 128 * 4;     // 25.6 MB
    const size_t sz_cac = (size_t)NN * 3 * 4;       // 600 KB
    const size_t sz_y   = (size_t)NN * 128 * 2;     // 12.8 MB each

    char* p = (char*)d_ws;
    short* wbf       = (short*)p;  p += sz_wb;
    float* aggr      = (float*)p;  p += sz_agg;
    float* coord_acc = (float*)p;  p += sz_cac;
    short* ysb       = (short*)p;  p += sz_y;
    short* ydb       = (short*)p;
    (void)ws_size;

    const int n4 = (NN * 128 + NN * 3) / 4;
    const int ng = (NN + 127) / 128;          // 391

    prep_kernel<<<(W_TOTAL + 255) / 256, 256, 0, stream>>>(We1, We2, Wn1, Wn2, Wc1, wbf);
    zero_kernel<<<2048, 256, 0, stream>>>((float4*)aggr, n4);
    ynode_kernel<<<ng, 256, 0, stream>>>(node_feat, wbf, ysb, ydb);

    edge_kernel<<<512, 256, 0, stream>>>(
        ysb, ydb, edge_attr, coords, edge_index, wbf,
        be1, be2, bc1, bc2, Wc2, aggr, coord_acc);

    node_kernel<<<ng, 256, 0, stream>>>(
        node_feat, coords, wbf, bn1, bn2, aggr, coord_acc, out);
}

// Round 12
// 378.982 us; speedup vs baseline: 1.1727x; 1.1727x over previous
//
#include <hip/hip_runtime.h>
#include <hip/hip_bf16.h>
#include <math.h>
#include <stdint.h>

#define NN 50000
#define NE 400000

typedef __attribute__((ext_vector_type(8))) short short8;
typedef __attribute__((ext_vector_type(4))) float f32x4;

// bf16 weight workspace layout (element offsets)
#define OFF_W1S  0           // [128][128]  We1 rows 0..127   (src half), transposed
#define OFF_W1D  16384       // [128][128]  We1 rows 128..255 (dst half)
#define OFF_W1E  32768       // [128][64]   We1 rows 256..319 (edge_attr part)
#define OFF_WE2T 40960       // [128][128]
#define OFF_WN1T 57344       // [128][256]
#define OFF_WN2T 90112       // [128][128]
#define OFF_WC1T 106496      // [64][128]
#define W_TOTAL  114688

__device__ __forceinline__ float silu_f(float x) {
    return x * (1.0f / (1.0f + __expf(-x)));
}
__device__ __forceinline__ short f2bf(float f) {
    __hip_bfloat16 b = __float2bfloat16(f);
    return *reinterpret_cast<short*>(&b);
}
__device__ __forceinline__ float bf2f(short s) {
    uint32_t u = ((uint32_t)(uint16_t)s) << 16;
    float f; __builtin_memcpy(&f, &u, 4); return f;
}
__device__ __forceinline__ uint32_t pk2(float lo, float hi) {
    return (uint32_t)(uint16_t)f2bf(lo) | ((uint32_t)(uint16_t)f2bf(hi) << 16);
}
__device__ __forceinline__ short8 cvt8(float4 a, float4 b) {
    short8 r;
    r[0] = f2bf(a.x); r[1] = f2bf(a.y); r[2] = f2bf(a.z); r[3] = f2bf(a.w);
    r[4] = f2bf(b.x); r[5] = f2bf(b.y); r[6] = f2bf(b.z); r[7] = f2bf(b.w);
    return r;
}

// C-pack -> B-fragment lane exchange (proven R4/R5/R9/R10).
__device__ __forceinline__ short8 exch8(uint32_t e0, uint32_t e1,
                                        uint32_t o0, uint32_t o1,
                                        int g, int le) {
    const int srcA = le + 16 * ((g & 1) * 2);
    const int srcB = srcA + 16;
    const uint32_t a0e = __shfl((int)e0, srcA), a0o = __shfl((int)o0, srcA);
    const uint32_t a1e = __shfl((int)e1, srcA), a1o = __shfl((int)o1, srcA);
    const uint32_t b0e = __shfl((int)e0, srcB), b0o = __shfl((int)o0, srcB);
    const uint32_t b1e = __shfl((int)e1, srcB), b1o = __shfl((int)o1, srcB);
    const bool hi = (g & 2) != 0;
    uint32_t v[4];
    v[0] = hi ? a0o : a0e;  v[1] = hi ? a1o : a1e;
    v[2] = hi ? b0o : b0e;  v[3] = hi ? b1o : b1e;
    short8 r; __builtin_memcpy(&r, v, 16); return r;
}

// ---------------- zero aggr/coord/cnt (contiguous region) ----------------
__global__ void zero_kernel(float4* __restrict__ p, int n4) {
    int i = blockIdx.x * blockDim.x + threadIdx.x;
    int st = gridDim.x * blockDim.x;
    for (; i < n4; i += st) p[i] = make_float4(0.f, 0.f, 0.f, 0.f);
}

// ---------------- prep: weights fp32 [K][N] -> bf16 transposed [N][K] ----------------
__global__ __launch_bounds__(256) void prep_kernel(
    const float* __restrict__ We1, const float* __restrict__ We2,
    const float* __restrict__ Wn1, const float* __restrict__ Wn2,
    const float* __restrict__ Wc1, short* __restrict__ wb)
{
    const int i = blockIdx.x * 256 + threadIdx.x;
    if (i >= W_TOTAL) return;
    float v; int rel, n, k;
    if (i < OFF_W1D)       { rel = i;            n = rel >> 7; k = rel & 127; v = We1[k * 128 + n]; }
    else if (i < OFF_W1E)  { rel = i - OFF_W1D;  n = rel >> 7; k = rel & 127; v = We1[(k + 128) * 128 + n]; }
    else if (i < OFF_WE2T) { rel = i - OFF_W1E;  n = rel >> 6; k = rel & 63;  v = We1[(k + 256) * 128 + n]; }
    else if (i < OFF_WN1T) { rel = i - OFF_WE2T; n = rel >> 7; k = rel & 127; v = We2[k * 128 + n]; }
    else if (i < OFF_WN2T) { rel = i - OFF_WN1T; n = rel >> 8; k = rel & 255; v = Wn1[k * 128 + n]; }
    else if (i < OFF_WC1T) { rel = i - OFF_WN2T; n = rel >> 7; k = rel & 127; v = Wn2[k * 128 + n]; }
    else                   { rel = i - OFF_WC1T; n = rel >> 7; k = rel & 127; v = Wc1[k * 64 + n]; }
    wb[i] = f2bf(v);
}

// ---------------- CSR build (R5-proven) ----------------
__global__ __launch_bounds__(256) void hist_kernel(const int* __restrict__ ei, int* __restrict__ cnt) {
    const int e = blockIdx.x * 256 + threadIdx.x;
    if (e < NE) atomicAdd(&cnt[ei[NE + e]], 1);
}

__global__ __launch_bounds__(256) void scanA_kernel(const int* __restrict__ cnt,
                                                    int* __restrict__ eoff, int* __restrict__ bsum) {
    __shared__ int sm[256];
    const int t = threadIdx.x, idx = blockIdx.x * 256 + t;
    const int v = (idx < NN) ? cnt[idx] : 0;
    sm[t] = v; __syncthreads();
    #pragma unroll
    for (int o = 1; o < 256; o <<= 1) {
        const int x = (t >= o) ? sm[t - o] : 0;
        __syncthreads();
        sm[t] += x;
        __syncthreads();
    }
    if (idx < NN) eoff[idx] = sm[t] - v;
    if (t == 255) bsum[blockIdx.x] = sm[255];
}

__global__ __launch_bounds__(256) void scanB_kernel(const int* __restrict__ bsum,
                                                    int* __restrict__ bexcl, int nb) {
    __shared__ int sm[256];
    const int t = threadIdx.x;
    const int v = (t < nb) ? bsum[t] : 0;
    sm[t] = v; __syncthreads();
    #pragma unroll
    for (int o = 1; o < 256; o <<= 1) {
        const int x = (t >= o) ? sm[t - o] : 0;
        __syncthreads();
        sm[t] += x;
        __syncthreads();
    }
    bexcl[t] = sm[t] - v;
}

__global__ __launch_bounds__(256) void scanC_kernel(const int* __restrict__ eoff,
                                                    const int* __restrict__ bexcl,
                                                    int* __restrict__ cursor) {
    const int idx = blockIdx.x * 256 + threadIdx.x;
    if (idx < NN) cursor[idx] = eoff[idx] + bexcl[blockIdx.x];
}

__global__ __launch_bounds__(256) void fill_kernel(const int* __restrict__ ei,
                                                   int* __restrict__ cursor, int* __restrict__ csr) {
    const int e = blockIdx.x * 256 + threadIdx.x;
    if (e < NE) {
        const int pos = atomicAdd(&cursor[ei[NE + e]], 1);
        csr[pos] = e;
    }
}

// ---------------- ynode: Ys = nf @ We1_src, Yd = nf @ We1_dst (bf16 out) ----------------
__global__ __launch_bounds__(256, 4) void ynode_kernel(
    const float* __restrict__ nf, const short* __restrict__ wb,
    short* __restrict__ ysb, short* __restrict__ ydb)
{
    const int tid = threadIdx.x;
    const int wv = tid >> 6, lane = tid & 63, le = lane & 15, grp = lane >> 4;
    const int nb = blockIdx.x * 128, wbase = wv * 32;
    const int row0 = min(nb + wbase + le, NN - 1);
    const int row1 = min(nb + wbase + 16 + le, NN - 1);

    #pragma unroll 1
    for (int pass = 0; pass < 2; ++pass) {
        const short* wt = wb + (pass ? OFF_W1D : OFF_W1S);
        short* op = pass ? ydb : ysb;

        f32x4 acc[2][8];
        #pragma unroll
        for (int m = 0; m < 2; ++m)
            #pragma unroll
            for (int t = 0; t < 8; ++t) acc[m][t] = (f32x4){0.f, 0.f, 0.f, 0.f};

        #pragma unroll
        for (int kc = 0; kc < 4; ++kc) {
            const int gk = kc * 32 + grp * 8;
            const float* p0 = nf + (size_t)row0 * 128 + gk;
            const float* p1 = nf + (size_t)row1 * 128 + gk;
            const short8 a0 = cvt8(*(const float4*)p0, *(const float4*)(p0 + 4));
            const short8 a1 = cvt8(*(const float4*)p1, *(const float4*)(p1 + 4));
            short8 bfv[8];
            #pragma unroll
            for (int t = 0; t < 8; ++t)
                bfv[t] = *(const short8*)(wt + (size_t)(t * 16 + le) * 128 + gk);
            #pragma unroll
            for (int t = 0; t < 8; ++t) {
                acc[0][t] = __builtin_amdgcn_mfma_f32_16x16x32_bf16(a0, bfv[t], acc[0][t], 0, 0, 0);
                acc[1][t] = __builtin_amdgcn_mfma_f32_16x16x32_bf16(a1, bfv[t], acc[1][t], 0, 0, 0);
            }
        }
        #pragma unroll
        for (int t = 0; t < 8; ++t)
            #pragma unroll
            for (int m = 0; m < 2; ++m)
                #pragma unroll
                for (int r = 0; r < 4; ++r) {
                    const int row = nb + wbase + m * 16 + grp * 4 + r;
                    if (row < NN)
                        op[(size_t)row * 128 + t * 16 + le] = f2bf(acc[m][t][r]);
                }
    }
}

// ---------------- edge pipeline: CSR-ordered + run-compressed atomics ----------------
// R10's proven structure (register gathers + exch8 + fp32 Ht tile), but edges
// come sorted by dst: a 16-edge tile spans ~2-3 dst rows, so the atomic scatter
// pre-sums runs of equal dst in registers and emits one 256B atomic pair per
// run (line-RMWs per tile: 128 -> ~24). Coord atomics run-compressed via shfl.
__global__ __launch_bounds__(256, 4) void edge_kernel(
    const short* __restrict__ ysb, const short* __restrict__ ydb,
    const float* __restrict__ ea, const float* __restrict__ coords,
    const int* __restrict__ ei, const int* __restrict__ csr,
    const short* __restrict__ wb,
    const float* __restrict__ be1, const float* __restrict__ be2,
    const float* __restrict__ bc1, const float* __restrict__ bc2,
    const float* __restrict__ Wc2f,
    float* __restrict__ aggr, float* __restrict__ coord_acc)
{
    __shared__ float Ht4[4][16 * 136];   // 8.5KB per wave, wave-private

    const int tid = threadIdx.x;
    const int wv = tid >> 6, lane = tid & 63, le = lane & 15, g = lane >> 4;
    const int e = csr[(blockIdx.x * 4 + wv) * 16 + le];
    float* Ht = Ht4[wv];

    const int s0 = ei[e], d0 = ei[NE + e];

    // register gathers: Ys[s0], Yd[d0] as B-frag chunks (cc=0..3), 16B per load
    short8 ys8[4], yd8[4];
    #pragma unroll
    for (int cc = 0; cc < 4; ++cc) {
        ys8[cc] = *(const short8*)(ysb + (size_t)s0 * 128 + cc * 32 + g * 8);
        yd8[cc] = *(const short8*)(ydb + (size_t)d0 * 128 + cc * 32 + g * 8);
    }

    // edge_attr B-frags (gathered 256B rows)
    short8 eaB[2];
    #pragma unroll
    for (int kc = 0; kc < 2; ++kc) {
        const float* pe = ea + (size_t)e * 64 + kc * 32 + g * 8;
        eaB[kc] = cvt8(*(const float4*)pe, *(const float4*)(pe + 4));
    }

    // ===== MLP1 ea-part (swapped): C lane le = edge, col t*16+g*4+r
    f32x4 acc[8];
    #pragma unroll
    for (int t = 0; t < 8; ++t) acc[t] = (f32x4){0.f, 0.f, 0.f, 0.f};

    const short* w1e = wb + OFF_W1E;
    #pragma unroll
    for (int kc = 0; kc < 2; ++kc) {
        const int gk = kc * 32 + g * 8;
        short8 wfv[8];
        #pragma unroll
        for (int t = 0; t < 8; ++t)
            wfv[t] = *(const short8*)(w1e + (size_t)(t * 16 + le) * 64 + gk);
        #pragma unroll
        for (int t = 0; t < 8; ++t)
            acc[t] = __builtin_amdgcn_mfma_f32_16x16x32_bf16(wfv[t], eaB[kc], acc[t], 0, 0, 0);
    }

    // pack ea-part C-frags to bf16 pairs
    uint32_t hp[8][2];
    #pragma unroll
    for (int t = 0; t < 8; ++t) {
        hp[t][0] = pk2(acc[t][0], acc[t][1]);
        hp[t][1] = pk2(acc[t][2], acc[t][3]);
    }

    // ===== h1 B-frags: exch(ea-part) + Ys + Yd + be1, silu — all in registers
    short8 h1f[4];
    #pragma unroll
    for (int cc = 0; cc < 4; ++cc) {
        const short8 ex = exch8(hp[cc*2][0], hp[cc*2][1], hp[cc*2+1][0], hp[cc*2+1][1], g, le);
        const float* bp = be1 + cc * 32 + g * 8;
        #pragma unroll
        for (int j = 0; j < 8; ++j)
            h1f[cc][j] = f2bf(silu_f(bf2f(ex[j]) + bf2f(ys8[cc][j]) + bf2f(yd8[cc][j]) + bp[j]));
    }

    // ===== MLP2 (swapped): acc2[t], K=128
    f32x4 acc2[8];
    #pragma unroll
    for (int t = 0; t < 8; ++t) acc2[t] = (f32x4){0.f, 0.f, 0.f, 0.f};

    const short* w2 = wb + OFF_WE2T;
    #pragma unroll
    for (int cc = 0; cc < 4; ++cc) {
        const int gk = cc * 32 + g * 8;
        short8 wfv[8];
        #pragma unroll
        for (int t = 0; t < 8; ++t)
            wfv[t] = *(const short8*)(w2 + (size_t)(t * 16 + le) * 128 + gk);
        #pragma unroll
        for (int t = 0; t < 8; ++t)
            acc2[t] = __builtin_amdgcn_mfma_f32_16x16x32_bf16(wfv[t], h1f[cc], acc2[t], 0, 0, 0);
    }

    // ===== h2 epilogue: fp32 -> LDS tile [edge][col] (wave-private, race-free)
    #pragma unroll
    for (int t = 0; t < 8; ++t) {
        #pragma unroll
        for (int r = 0; r < 4; ++r) {
            const int col = t * 16 + g * 4 + r;
            Ht[le * 136 + col] = silu_f(acc2[t][r] + be2[col]);
        }
    }

    // ===== run-compressed feature scatter (edges sorted by dst):
    // lane owns cols c0 = g*16+le (0..63) and c1 = c0+64; serial wave-uniform
    // scan over the 16 rows accumulates runs of equal dst, one atomic pair/run.
    {
        const int c0 = g * 16 + le;
        const int c1 = c0 + 64;
        float a0 = 0.f, a1 = 0.f;
        int dprev = __shfl(d0, 0);
        #pragma unroll 1
        for (int row = 0; row < 16; ++row) {
            const int dr = __shfl(d0, row);
            if (dr != dprev) {
                atomicAdd(&aggr[(size_t)dprev * 128 + c0], a0);
                atomicAdd(&aggr[(size_t)dprev * 128 + c1], a1);
                a0 = 0.f; a1 = 0.f;
                dprev = dr;
            }
            a0 += Ht[row * 136 + c0];
            a1 += Ht[row * 136 + c1];
        }
        atomicAdd(&aggr[(size_t)dprev * 128 + c0], a0);
        atomicAdd(&aggr[(size_t)dprev * 128 + c1], a1);
    }

    // h2 B-frags for coord MLP from the fp32 tile
    short8 h2f[4];
    #pragma unroll
    for (int cc = 0; cc < 4; ++cc) {
        const float* hq = &Ht[le * 136 + cc * 32 + g * 8];
        h2f[cc] = cvt8(*(const float4*)hq, *(const float4*)(hq + 4));
    }

    // ===== coord MLP (swapped), N=64: acc3[t=0..3]
    f32x4 acc3[4];
    #pragma unroll
    for (int t = 0; t < 4; ++t) acc3[t] = (f32x4){0.f, 0.f, 0.f, 0.f};

    const short* wc = wb + OFF_WC1T;
    #pragma unroll
    for (int cc = 0; cc < 4; ++cc) {
        const int gk = cc * 32 + g * 8;
        short8 wfv[4];
        #pragma unroll
        for (int t = 0; t < 4; ++t)
            wfv[t] = *(const short8*)(wc + (size_t)(t * 16 + le) * 128 + gk);
        #pragma unroll
        for (int t = 0; t < 4; ++t)
            acc3[t] = __builtin_amdgcn_mfma_f32_16x16x32_bf16(wfv[t], h2f[cc], acc3[t], 0, 0, 0);
    }

    // coord_w: per-lane partial over cols, reduce across the 4 g-lanes
    float part = 0.f;
    #pragma unroll
    for (int t = 0; t < 4; ++t)
        #pragma unroll
        for (int r = 0; r < 4; ++r) {
            const int col = t * 16 + g * 4 + r;
            part += silu_f(acc3[t][r] + bc1[col]) * Wc2f[col];
        }
    part += __shfl_xor(part, 16);
    part += __shfl_xor(part, 32);

    // per-edge equivariant vector (all lanes compute; depends on le only)
    const float wq = part + bc2[0];
    const float dx = coords[3 * s0 + 0] - coords[3 * d0 + 0];
    const float dy = coords[3 * s0 + 1] - coords[3 * d0 + 1];
    const float dz = coords[3 * s0 + 2] - coords[3 * d0 + 2];
    const float inv = wq / (sqrtf(dx * dx + dy * dy + dz * dz) + 1e-8f);
    float vx = dx * inv, vy = dy * inv, vz = dz * inv;

    // run-compressed coord scatter: head lanes sum their run via shfl gather
    {
        const int prevd = __shfl(d0, (le == 0) ? 0 : (le - 1));
        const bool head = (le == 0) || (prevd != d0);
        float sx = vx, sy = vy, sz = vz;
        #pragma unroll 1
        for (int j = 1; j < 16; ++j) {
            const float tx = __shfl(vx, le + j);
            const float ty = __shfl(vy, le + j);
            const float tz = __shfl(vz, le + j);
            const int dj = __shfl(d0, le + j);
            if ((le + j < 16) && (dj == d0)) { sx += tx; sy += ty; sz += tz; }
        }
        if (g == 0 && head) {
            atomicAdd(&coord_acc[3 * d0 + 0], sx);
            atomicAdd(&coord_acc[3 * d0 + 1], sy);
            atomicAdd(&coord_acc[3 * d0 + 2], sz);
        }
    }
}

// ---------------- node update (MFMA, barrier-free, fp32 inputs) ----------------
__global__ __launch_bounds__(256, 2) void node_kernel(
    const float* __restrict__ nf, const float* __restrict__ coords,
    const short* __restrict__ wb,
    const float* __restrict__ bn1, const float* __restrict__ bn2,
    const float* __restrict__ aggr, const float* __restrict__ coord_acc,
    float* __restrict__ out)
{
    __shared__ short Hs[128][136];

    const int tid = threadIdx.x;
    const int wv = tid >> 6, lane = tid & 63, le = lane & 15, grp = lane >> 4;
    const int nb = blockIdx.x * 128, wbase = wv * 32;
    const int row0 = min(nb + wbase + le, NN - 1);
    const int row1 = min(nb + wbase + 16 + le, NN - 1);

    f32x4 acc[2][8];
    #pragma unroll
    for (int m = 0; m < 2; ++m)
        #pragma unroll
        for (int t = 0; t < 8; ++t) acc[m][t] = (f32x4){0.f, 0.f, 0.f, 0.f};

    const short* w1 = wb + OFF_WN1T;
    #pragma unroll
    for (int kc = 0; kc < 8; ++kc) {
        const int gk = kc * 32 + grp * 8;
        const float* p0 = (kc < 4) ? nf + (size_t)row0 * 128 + gk : aggr + (size_t)row0 * 128 + gk - 128;
        const float* p1 = (kc < 4) ? nf + (size_t)row1 * 128 + gk : aggr + (size_t)row1 * 128 + gk - 128;
        const short8 a0 = cvt8(*(const float4*)p0, *(const float4*)(p0 + 4));
        const short8 a1 = cvt8(*(const float4*)p1, *(const float4*)(p1 + 4));
        short8 bfv[8];
        #pragma unroll
        for (int t = 0; t < 8; ++t)
            bfv[t] = *(const short8*)(w1 + (size_t)(t * 16 + le) * 256 + gk);
        #pragma unroll
        for (int t = 0; t < 8; ++t) {
            acc[0][t] = __builtin_amdgcn_mfma_f32_16x16x32_bf16(a0, bfv[t], acc[0][t], 0, 0, 0);
            acc[1][t] = __builtin_amdgcn_mfma_f32_16x16x32_bf16(a1, bfv[t], acc[1][t], 0, 0, 0);
        }
    }
    #pragma unroll
    for (int t = 0; t < 8; ++t) {
        const float b1 = bn1[t * 16 + le];
        #pragma unroll
        for (int m = 0; m < 2; ++m)
            #pragma unroll
            for (int r = 0; r < 4; ++r)
                Hs[wbase + m * 16 + grp * 4 + r][t * 16 + le] = f2bf(silu_f(acc[m][t][r] + b1));
    }

    f32x4 acc2[2][8];
    #pragma unroll
    for (int m = 0; m < 2; ++m)
        #pragma unroll
        for (int t = 0; t < 8; ++t) acc2[m][t] = (f32x4){0.f, 0.f, 0.f, 0.f};

    const short* w2 = wb + OFF_WN2T;
    #pragma unroll
    for (int kc = 0; kc < 4; ++kc) {
        const int gk = kc * 32 + grp * 8;
        const short8 a0 = *(const short8*)&Hs[wbase + le][gk];
        const short8 a1 = *(const short8*)&Hs[wbase + 16 + le][gk];
        short8 bfv[8];
        #pragma unroll
        for (int t = 0; t < 8; ++t)
            bfv[t] = *(const short8*)(w2 + (size_t)(t * 16 + le) * 128 + gk);
        #pragma unroll
        for (int t = 0; t < 8; ++t) {
            acc2[0][t] = __builtin_amdgcn_mfma_f32_16x16x32_bf16(a0, bfv[t], acc2[0][t], 0, 0, 0);
            acc2[1][t] = __builtin_amdgcn_mfma_f32_16x16x32_bf16(a1, bfv[t], acc2[1][t], 0, 0, 0);
        }
    }
    #pragma unroll
    for (int t = 0; t < 8; ++t) {
        const float b2 = bn2[t * 16 + le];
        #pragma unroll
        for (int m = 0; m < 2; ++m)
            #pragma unroll
            for (int r = 0; r < 4; ++r) {
                const int row = nb + wbase + m * 16 + grp * 4 + r;
                if (row < NN) {
                    const int c = t * 16 + le;
                    out[(size_t)row * 128 + c] = acc2[m][t][r] + b2 + nf[(size_t)row * 128 + c];
                }
            }
    }

    for (int i = tid; i < 384; i += 256) {
        const int n = nb + i / 3, j = i % 3;
        if (n < NN)
            out[(size_t)NN * 128 + 3 * n + j] = coords[3 * n + j] + coord_acc[3 * n + j];
    }
}

extern "C" void kernel_launch(void* const* d_in, const int* in_sizes, int n_in,
                              void* d_out, int out_size, void* d_ws, size_t ws_size,
                              hipStream_t stream)
{
    const float* node_feat  = (const float*)d_in[0];
    const float* edge_attr  = (const float*)d_in[1];
    const float* coords     = (const float*)d_in[2];
    const int*   edge_index = (const int*)d_in[3];
    const float* We1 = (const float*)d_in[4];
    const float* be1 = (const float*)d_in[5];
    const float* We2 = (const float*)d_in[6];
    const float* be2 = (const float*)d_in[7];
    const float* Wn1 = (const float*)d_in[8];
    const float* bn1 = (const float*)d_in[9];
    const float* Wn2 = (const float*)d_in[10];
    const float* bn2 = (const float*)d_in[11];
    const float* Wc1 = (const float*)d_in[12];
    const float* bc1 = (const float*)d_in[13];
    const float* Wc2 = (const float*)d_in[14];
    const float* bc2 = (const float*)d_in[15];
    float* out = (float*)d_out;

    const size_t sz_wb  = (size_t)W_TOTAL * 2;      // 229 KB
    const size_t sz_agg = (size_t)NN * 128 * 4;     // 25.6 MB
    const size_t sz_cac = (size_t)NN * 3 * 4;       // 600 KB
    const size_t sz_cnt = (size_t)NN * 4;           // 200 KB
    const size_t sz_y   = (size_t)NN * 128 * 2;     // 12.8 MB each

    char* p = (char*)d_ws;
    short* wbf       = (short*)p;  p += sz_wb;
    float* aggr      = (float*)p;  p += sz_agg;     // aggr, coord_acc, cnt contiguous
    float* coord_acc = (float*)p;  p += sz_cac;     //   (one zero_kernel pass)
    int*   cnt       = (int*)p;    p += sz_cnt;
    short* ysb       = (short*)p;  p += sz_y;
    short* ydb       = (short*)p;  p += sz_y;
    int*   eoff      = (int*)p;    p += (size_t)NN * 4;
    int*   bsum      = (int*)p;    p += 1024;
    int*   bexcl     = (int*)p;    p += 1024;
    int*   cursor    = (int*)p;    p += (size_t)NN * 4;
    int*   csr       = (int*)p;
    (void)ws_size;

    const int n4 = (NN * 128 + NN * 3 + NN) / 4;  // aggr + coord_acc + cnt
    const int eg = NE / 64;                       // 6250 blocks (4 waves x 16 edges)
    const int ng = (NN + 127) / 128;              // 391
    const int eg256 = (NE + 255) / 256;           // 1563
    const int sg = (NN + 255) / 256;              // 196

    prep_kernel<<<(W_TOTAL + 255) / 256, 256, 0, stream>>>(We1, We2, Wn1, Wn2, Wc1, wbf);
    zero_kernel<<<2048, 256, 0, stream>>>((float4*)aggr, n4);
    ynode_kernel<<<ng, 256, 0, stream>>>(node_feat, wbf, ysb, ydb);

    hist_kernel<<<eg256, 256, 0, stream>>>(edge_index, cnt);
    scanA_kernel<<<sg, 256, 0, stream>>>(cnt, eoff, bsum);
    scanB_kernel<<<1, 256, 0, stream>>>(bsum, bexcl, sg);
    scanC_kernel<<<sg, 256, 0, stream>>>(eoff, bexcl, cursor);
    fill_kernel<<<eg256, 256, 0, stream>>>(edge_index, cursor, csr);

    edge_kernel<<<eg, 256, 0, stream>>>(
        ysb, ydb, edge_attr, coords, edge_index, csr, wbf,
        be1, be2, bc1, bc2, Wc2, aggr, coord_acc);

    node_kernel<<<ng, 256, 0, stream>>>(
        node_feat, coords, wbf, bn1, bn2, aggr, coord_acc, out);
}

// Round 13
// 358.083 us; speedup vs baseline: 1.2412x; 1.0584x over previous
//
#include <hip/hip_runtime.h>
#include <hip/hip_bf16.h>
#include <math.h>
#include <stdint.h>

#define NN 50000
#define NE 400000

typedef __attribute__((ext_vector_type(8))) short short8;
typedef __attribute__((ext_vector_type(4))) float f32x4;

// bf16 weight workspace layout (element offsets)
#define OFF_W1S  0           // [128][128]  We1 rows 0..127   (src half), transposed
#define OFF_W1D  16384       // [128][128]  We1 rows 128..255 (dst half)
#define OFF_W1E  32768       // [128][64]   We1 rows 256..319 (edge_attr part)
#define OFF_WE2T 40960       // [128][128]
#define OFF_WN1T 57344       // [128][256]
#define OFF_WN2T 90112       // [128][128]
#define OFF_WC1T 106496      // [64][128]
#define W_TOTAL  114688

#define NZ4 ((NN * 128 + NN * 3 + NN) / 4)   // aggr + coord_acc + cnt, in float4s

__device__ __forceinline__ float silu_f(float x) {
    return x * (1.0f / (1.0f + __expf(-x)));
}
__device__ __forceinline__ short f2bf(float f) {
    __hip_bfloat16 b = __float2bfloat16(f);
    return *reinterpret_cast<short*>(&b);
}
__device__ __forceinline__ float bf2f(short s) {
    uint32_t u = ((uint32_t)(uint16_t)s) << 16;
    float f; __builtin_memcpy(&f, &u, 4); return f;
}
__device__ __forceinline__ uint32_t pk2(float lo, float hi) {
    return (uint32_t)(uint16_t)f2bf(lo) | ((uint32_t)(uint16_t)f2bf(hi) << 16);
}
__device__ __forceinline__ short8 cvt8(float4 a, float4 b) {
    short8 r;
    r[0] = f2bf(a.x); r[1] = f2bf(a.y); r[2] = f2bf(a.z); r[3] = f2bf(a.w);
    r[4] = f2bf(b.x); r[5] = f2bf(b.y); r[6] = f2bf(b.z); r[7] = f2bf(b.w);
    return r;
}

// C-pack -> B-fragment lane exchange (proven R4..R12).
__device__ __forceinline__ short8 exch8(uint32_t e0, uint32_t e1,
                                        uint32_t o0, uint32_t o1,
                                        int g, int le) {
    const int srcA = le + 16 * ((g & 1) * 2);
    const int srcB = srcA + 16;
    const uint32_t a0e = __shfl((int)e0, srcA), a0o = __shfl((int)o0, srcA);
    const uint32_t a1e = __shfl((int)e1, srcA), a1o = __shfl((int)o1, srcA);
    const uint32_t b0e = __shfl((int)e0, srcB), b0o = __shfl((int)o0, srcB);
    const uint32_t b1e = __shfl((int)e1, srcB), b1o = __shfl((int)o1, srcB);
    const bool hi = (g & 2) != 0;
    uint32_t v[4];
    v[0] = hi ? a0o : a0e;  v[1] = hi ? a1o : a1e;
    v[2] = hi ? b0o : b0e;  v[3] = hi ? b1o : b1e;
    short8 r; __builtin_memcpy(&r, v, 16); return r;
}

// ---------------- prep: weight transpose->bf16 + zero accumulators ----------------
__global__ __launch_bounds__(256) void prep_kernel(
    const float* __restrict__ We1, const float* __restrict__ We2,
    const float* __restrict__ Wn1, const float* __restrict__ Wn2,
    const float* __restrict__ Wc1, short* __restrict__ wb,
    float4* __restrict__ zbase)
{
    const int i = blockIdx.x * 256 + threadIdx.x;
    if (i < W_TOTAL) {
        float v; int rel, n, k;
        if (i < OFF_W1D)       { rel = i;            n = rel >> 7; k = rel & 127; v = We1[k * 128 + n]; }
        else if (i < OFF_W1E)  { rel = i - OFF_W1D;  n = rel >> 7; k = rel & 127; v = We1[(k + 128) * 128 + n]; }
        else if (i < OFF_WE2T) { rel = i - OFF_W1E;  n = rel >> 6; k = rel & 63;  v = We1[(k + 256) * 128 + n]; }
        else if (i < OFF_WN1T) { rel = i - OFF_WE2T; n = rel >> 7; k = rel & 127; v = We2[k * 128 + n]; }
        else if (i < OFF_WN2T) { rel = i - OFF_WN1T; n = rel >> 8; k = rel & 255; v = Wn1[k * 128 + n]; }
        else if (i < OFF_WC1T) { rel = i - OFF_WN2T; n = rel >> 7; k = rel & 127; v = Wn2[k * 128 + n]; }
        else                   { rel = i - OFF_WC1T; n = rel >> 7; k = rel & 127; v = Wc1[k * 64 + n]; }
        wb[i] = f2bf(v);
    } else if (i < W_TOTAL + NZ4) {
        zbase[i - W_TOTAL] = make_float4(0.f, 0.f, 0.f, 0.f);
    }
}

// ---------------- CSR build (R5/R12-proven) ----------------
__global__ __launch_bounds__(256) void hist_kernel(const int* __restrict__ ei, int* __restrict__ cnt) {
    const int e = blockIdx.x * 256 + threadIdx.x;
    if (e < NE) atomicAdd(&cnt[ei[NE + e]], 1);
}

__global__ __launch_bounds__(256) void scanA_kernel(const int* __restrict__ cnt,
                                                    int* __restrict__ eoff, int* __restrict__ bsum) {
    __shared__ int sm[256];
    const int t = threadIdx.x, idx = blockIdx.x * 256 + t;
    const int v = (idx < NN) ? cnt[idx] : 0;
    sm[t] = v; __syncthreads();
    #pragma unroll
    for (int o = 1; o < 256; o <<= 1) {
        const int x = (t >= o) ? sm[t - o] : 0;
        __syncthreads();
        sm[t] += x;
        __syncthreads();
    }
    if (idx < NN) eoff[idx] = sm[t] - v;
    if (t == 255) bsum[blockIdx.x] = sm[255];
}

__global__ __launch_bounds__(256) void scanB_kernel(const int* __restrict__ bsum,
                                                    int* __restrict__ bexcl, int nb) {
    __shared__ int sm[256];
    const int t = threadIdx.x;
    const int v = (t < nb) ? bsum[t] : 0;
    sm[t] = v; __syncthreads();
    #pragma unroll
    for (int o = 1; o < 256; o <<= 1) {
        const int x = (t >= o) ? sm[t - o] : 0;
        __syncthreads();
        sm[t] += x;
        __syncthreads();
    }
    bexcl[t] = sm[t] - v;
}

__global__ __launch_bounds__(256) void scanC_kernel(const int* __restrict__ eoff,
                                                    const int* __restrict__ bexcl,
                                                    int* __restrict__ cursor) {
    const int idx = blockIdx.x * 256 + threadIdx.x;
    if (idx < NN) cursor[idx] = eoff[idx] + bexcl[blockIdx.x];
}

__global__ __launch_bounds__(256) void fill_kernel(const int* __restrict__ ei,
                                                   int* __restrict__ cursor, int* __restrict__ csr) {
    const int e = blockIdx.x * 256 + threadIdx.x;
    if (e < NE) {
        const int pos = atomicAdd(&cursor[ei[NE + e]], 1);
        csr[pos] = e;
    }
}

// ---------------- ynode: Ys = nf @ We1_src, Yd = nf @ We1_dst (bf16 out) ----------------
__global__ __launch_bounds__(256, 4) void ynode_kernel(
    const float* __restrict__ nf, const short* __restrict__ wb,
    short* __restrict__ ysb, short* __restrict__ ydb)
{
    const int tid = threadIdx.x;
    const int wv = tid >> 6, lane = tid & 63, le = lane & 15, grp = lane >> 4;
    const int nb = blockIdx.x * 128, wbase = wv * 32;
    const int row0 = min(nb + wbase + le, NN - 1);
    const int row1 = min(nb + wbase + 16 + le, NN - 1);

    #pragma unroll 1
    for (int pass = 0; pass < 2; ++pass) {
        const short* wt = wb + (pass ? OFF_W1D : OFF_W1S);
        short* op = pass ? ydb : ysb;

        f32x4 acc[2][8];
        #pragma unroll
        for (int m = 0; m < 2; ++m)
            #pragma unroll
            for (int t = 0; t < 8; ++t) acc[m][t] = (f32x4){0.f, 0.f, 0.f, 0.f};

        #pragma unroll
        for (int kc = 0; kc < 4; ++kc) {
            const int gk = kc * 32 + grp * 8;
            const float* p0 = nf + (size_t)row0 * 128 + gk;
            const float* p1 = nf + (size_t)row1 * 128 + gk;
            const short8 a0 = cvt8(*(const float4*)p0, *(const float4*)(p0 + 4));
            const short8 a1 = cvt8(*(const float4*)p1, *(const float4*)(p1 + 4));
            short8 bfv[8];
            #pragma unroll
            for (int t = 0; t < 8; ++t)
                bfv[t] = *(const short8*)(wt + (size_t)(t * 16 + le) * 128 + gk);
            #pragma unroll
            for (int t = 0; t < 8; ++t) {
                acc[0][t] = __builtin_amdgcn_mfma_f32_16x16x32_bf16(a0, bfv[t], acc[0][t], 0, 0, 0);
                acc[1][t] = __builtin_amdgcn_mfma_f32_16x16x32_bf16(a1, bfv[t], acc[1][t], 0, 0, 0);
            }
        }
        #pragma unroll
        for (int t = 0; t < 8; ++t)
            #pragma unroll
            for (int m = 0; m < 2; ++m)
                #pragma unroll
                for (int r = 0; r < 4; ++r) {
                    const int row = nb + wbase + m * 16 + grp * 4 + r;
                    if (row < NN)
                        op[(size_t)row * 128 + t * 16 + le] = f2bf(acc[m][t][r]);
                }
    }
}

// ---------------- edge pipeline: M=32, CSR-ordered, run-compressed atomics ----------------
// 128 edges/block, 4 waves, 32 edges/wave (two 16-edge B-tiles A,B). Each weight
// fragment load feeds BOTH tiles' MFMAs -> weight loads per edge halved vs R12.
// fp32 Ht tile (16 rows) used in two sequential scatter phases. Run-compressed
// atomics (R12-proven, WRITE 40 MB).
__global__ __launch_bounds__(256, 3) void edge_kernel(
    const short* __restrict__ ysb, const short* __restrict__ ydb,
    const float* __restrict__ ea, const float* __restrict__ coords,
    const int* __restrict__ ei, const int* __restrict__ csr,
    const short* __restrict__ wb,
    const float* __restrict__ be1, const float* __restrict__ be2,
    const float* __restrict__ bc1, const float* __restrict__ bc2,
    const float* __restrict__ Wc2f,
    float* __restrict__ aggr, float* __restrict__ coord_acc)
{
    __shared__ float Ht4[4][16 * 136];   // 8.5KB per wave, wave-private

    const int tid = threadIdx.x;
    const int wv = tid >> 6, lane = tid & 63, le = lane & 15, g = lane >> 4;
    const int base = (blockIdx.x * 4 + wv) * 32;
    float* Ht = Ht4[wv];

    const int eA = csr[base + le], eB = csr[base + 16 + le];
    const int sA = ei[eA], dA = ei[NE + eA];
    const int sB = ei[eB], dB = ei[NE + eB];

    // register gathers: Ys/Yd rows for both tiles (16B per load)
    short8 ysA[4], ydA[4], ysB[4], ydB8[4];
    #pragma unroll
    for (int cc = 0; cc < 4; ++cc) {
        ysA[cc]  = *(const short8*)(ysb + (size_t)sA * 128 + cc * 32 + g * 8);
        ydA[cc]  = *(const short8*)(ydb + (size_t)dA * 128 + cc * 32 + g * 8);
        ysB[cc]  = *(const short8*)(ysb + (size_t)sB * 128 + cc * 32 + g * 8);
        ydB8[cc] = *(const short8*)(ydb + (size_t)dB * 128 + cc * 32 + g * 8);
    }

    // edge_attr B-frags (fp32 row gathers)
    short8 eaA[2], eaB2[2];
    #pragma unroll
    for (int kc = 0; kc < 2; ++kc) {
        const float* pA = ea + (size_t)eA * 64 + kc * 32 + g * 8;
        const float* pB = ea + (size_t)eB * 64 + kc * 32 + g * 8;
        eaA[kc]  = cvt8(*(const float4*)pA, *(const float4*)(pA + 4));
        eaB2[kc] = cvt8(*(const float4*)pB, *(const float4*)(pB + 4));
    }

    // ===== MLP1 ea-part (swapped), both tiles share weight fragments
    f32x4 accA[8], accB[8];
    #pragma unroll
    for (int t = 0; t < 8; ++t) { accA[t] = (f32x4){0.f,0.f,0.f,0.f}; accB[t] = (f32x4){0.f,0.f,0.f,0.f}; }

    const short* w1e = wb + OFF_W1E;
    #pragma unroll
    for (int kc = 0; kc < 2; ++kc) {
        const int gk = kc * 32 + g * 8;
        short8 wfv[8];
        #pragma unroll
        for (int t = 0; t < 8; ++t)
            wfv[t] = *(const short8*)(w1e + (size_t)(t * 16 + le) * 64 + gk);
        #pragma unroll
        for (int t = 0; t < 8; ++t) {
            accA[t] = __builtin_amdgcn_mfma_f32_16x16x32_bf16(wfv[t], eaA[kc],  accA[t], 0, 0, 0);
            accB[t] = __builtin_amdgcn_mfma_f32_16x16x32_bf16(wfv[t], eaB2[kc], accB[t], 0, 0, 0);
        }
    }

    uint32_t hpA[8][2], hpB[8][2];
    #pragma unroll
    for (int t = 0; t < 8; ++t) {
        hpA[t][0] = pk2(accA[t][0], accA[t][1]);  hpA[t][1] = pk2(accA[t][2], accA[t][3]);
        hpB[t][0] = pk2(accB[t][0], accB[t][1]);  hpB[t][1] = pk2(accB[t][2], accB[t][3]);
    }

    // ===== h1 B-frags: exch + Ys + Yd + be1, silu
    short8 h1A[4], h1B[4];
    #pragma unroll
    for (int cc = 0; cc < 4; ++cc) {
        const short8 exA = exch8(hpA[cc*2][0], hpA[cc*2][1], hpA[cc*2+1][0], hpA[cc*2+1][1], g, le);
        const short8 exB = exch8(hpB[cc*2][0], hpB[cc*2][1], hpB[cc*2+1][0], hpB[cc*2+1][1], g, le);
        const float* bp = be1 + cc * 32 + g * 8;
        #pragma unroll
        for (int j = 0; j < 8; ++j) {
            h1A[cc][j] = f2bf(silu_f(bf2f(exA[j]) + bf2f(ysA[cc][j]) + bf2f(ydA[cc][j])  + bp[j]));
            h1B[cc][j] = f2bf(silu_f(bf2f(exB[j]) + bf2f(ysB[cc][j]) + bf2f(ydB8[cc][j]) + bp[j]));
        }
    }

    // ===== MLP2 (swapped), K=128, shared weight fragments
    f32x4 a2A[8], a2B[8];
    #pragma unroll
    for (int t = 0; t < 8; ++t) { a2A[t] = (f32x4){0.f,0.f,0.f,0.f}; a2B[t] = (f32x4){0.f,0.f,0.f,0.f}; }

    const short* w2 = wb + OFF_WE2T;
    #pragma unroll
    for (int cc = 0; cc < 4; ++cc) {
        const int gk = cc * 32 + g * 8;
        short8 wfv[8];
        #pragma unroll
        for (int t = 0; t < 8; ++t)
            wfv[t] = *(const short8*)(w2 + (size_t)(t * 16 + le) * 128 + gk);
        #pragma unroll
        for (int t = 0; t < 8; ++t) {
            a2A[t] = __builtin_amdgcn_mfma_f32_16x16x32_bf16(wfv[t], h1A[cc], a2A[t], 0, 0, 0);
            a2B[t] = __builtin_amdgcn_mfma_f32_16x16x32_bf16(wfv[t], h1B[cc], a2B[t], 0, 0, 0);
        }
    }

    // ===== h2 phases: Ht tile + run-compressed scatter, tile A then tile B
    uint32_t hqA[8][2], hqB[8][2];
    #pragma unroll 1
    for (int ph = 0; ph < 2; ++ph) {
        const f32x4* a2 = ph ? a2B : a2A;
        const int dt = ph ? dB : dA;
        uint32_t (*hq)[2] = ph ? hqB : hqA;

        #pragma unroll
        for (int t = 0; t < 8; ++t) {
            float hv[4];
            #pragma unroll
            for (int r = 0; r < 4; ++r) {
                const int col = t * 16 + g * 4 + r;
                hv[r] = silu_f(a2[t][r] + be2[col]);
                Ht[le * 136 + col] = hv[r];
            }
            hq[t][0] = pk2(hv[0], hv[1]);
            hq[t][1] = pk2(hv[2], hv[3]);
        }

        // run-compressed feature scatter (rows sorted by dst)
        const int c0 = g * 16 + le;
        const int c1 = c0 + 64;
        float a0 = 0.f, a1 = 0.f;
        int dprev = __shfl(dt, 0);
        #pragma unroll 1
        for (int row = 0; row < 16; ++row) {
            const int dr = __shfl(dt, row);
            if (dr != dprev) {
                atomicAdd(&aggr[(size_t)dprev * 128 + c0], a0);
                atomicAdd(&aggr[(size_t)dprev * 128 + c1], a1);
                a0 = 0.f; a1 = 0.f;
                dprev = dr;
            }
            a0 += Ht[row * 136 + c0];
            a1 += Ht[row * 136 + c1];
        }
        atomicAdd(&aggr[(size_t)dprev * 128 + c0], a0);
        atomicAdd(&aggr[(size_t)dprev * 128 + c1], a1);
    }

    // ===== coord MLP (swapped), N=64, shared weight fragments
    short8 h2A[4], h2B[4];
    #pragma unroll
    for (int cc = 0; cc < 4; ++cc) {
        h2A[cc] = exch8(hqA[cc*2][0], hqA[cc*2][1], hqA[cc*2+1][0], hqA[cc*2+1][1], g, le);
        h2B[cc] = exch8(hqB[cc*2][0], hqB[cc*2][1], hqB[cc*2+1][0], hqB[cc*2+1][1], g, le);
    }

    f32x4 c3A[4], c3B[4];
    #pragma unroll
    for (int t = 0; t < 4; ++t) { c3A[t] = (f32x4){0.f,0.f,0.f,0.f}; c3B[t] = (f32x4){0.f,0.f,0.f,0.f}; }

    const short* wc = wb + OFF_WC1T;
    #pragma unroll
    for (int cc = 0; cc < 4; ++cc) {
        const int gk = cc * 32 + g * 8;
        short8 wfv[4];
        #pragma unroll
        for (int t = 0; t < 4; ++t)
            wfv[t] = *(const short8*)(wc + (size_t)(t * 16 + le) * 128 + gk);
        #pragma unroll
        for (int t = 0; t < 4; ++t) {
            c3A[t] = __builtin_amdgcn_mfma_f32_16x16x32_bf16(wfv[t], h2A[cc], c3A[t], 0, 0, 0);
            c3B[t] = __builtin_amdgcn_mfma_f32_16x16x32_bf16(wfv[t], h2B[cc], c3B[t], 0, 0, 0);
        }
    }

    float partA = 0.f, partB = 0.f;
    #pragma unroll
    for (int t = 0; t < 4; ++t)
        #pragma unroll
        for (int r = 0; r < 4; ++r) {
            const int col = t * 16 + g * 4 + r;
            const float bc = bc1[col], wv2 = Wc2f[col];
            partA += silu_f(c3A[t][r] + bc) * wv2;
            partB += silu_f(c3B[t][r] + bc) * wv2;
        }
    partA += __shfl_xor(partA, 16); partA += __shfl_xor(partA, 32);
    partB += __shfl_xor(partB, 16); partB += __shfl_xor(partB, 32);

    // per-edge equivariant vectors + run-compressed coord scatter (per tile)
    #pragma unroll 1
    for (int ph = 0; ph < 2; ++ph) {
        const int s0 = ph ? sB : sA, d0 = ph ? dB : dA;
        const float wq = (ph ? partB : partA) + bc2[0];
        const float dx = coords[3 * s0 + 0] - coords[3 * d0 + 0];
        const float dy = coords[3 * s0 + 1] - coords[3 * d0 + 1];
        const float dz = coords[3 * s0 + 2] - coords[3 * d0 + 2];
        const float inv = wq / (sqrtf(dx * dx + dy * dy + dz * dz) + 1e-8f);
        float vx = dx * inv, vy = dy * inv, vz = dz * inv;

        const int prevd = __shfl(d0, (le == 0) ? 0 : (le - 1));
        const bool head = (le == 0) || (prevd != d0);
        float sx = vx, sy = vy, sz = vz;
        #pragma unroll 1
        for (int j = 1; j < 16; ++j) {
            const float tx = __shfl(vx, le + j);
            const float ty = __shfl(vy, le + j);
            const float tz = __shfl(vz, le + j);
            const int dj = __shfl(d0, le + j);
            if ((le + j < 16) && (dj == d0)) { sx += tx; sy += ty; sz += tz; }
        }
        if (g == 0 && head) {
            atomicAdd(&coord_acc[3 * d0 + 0], sx);
            atomicAdd(&coord_acc[3 * d0 + 1], sy);
            atomicAdd(&coord_acc[3 * d0 + 2], sz);
        }
    }
}

// ---------------- node update (MFMA, barrier-free, fp32 inputs) ----------------
__global__ __launch_bounds__(256, 3) void node_kernel(
    const float* __restrict__ nf, const float* __restrict__ coords,
    const short* __restrict__ wb,
    const float* __restrict__ bn1, const float* __restrict__ bn2,
    const float* __restrict__ aggr, const float* __restrict__ coord_acc,
    float* __restrict__ out)
{
    __shared__ short Hs[128][136];

    const int tid = threadIdx.x;
    const int wv = tid >> 6, lane = tid & 63, le = lane & 15, grp = lane >> 4;
    const int nb = blockIdx.x * 128, wbase = wv * 32;
    const int row0 = min(nb + wbase + le, NN - 1);
    const int row1 = min(nb + wbase + 16 + le, NN - 1);

    f32x4 acc[2][8];
    #pragma unroll
    for (int m = 0; m < 2; ++m)
        #pragma unroll
        for (int t = 0; t < 8; ++t) acc[m][t] = (f32x4){0.f, 0.f, 0.f, 0.f};

    const short* w1 = wb + OFF_WN1T;
    #pragma unroll
    for (int kc = 0; kc < 8; ++kc) {
        const int gk = kc * 32 + grp * 8;
        const float* p0 = (kc < 4) ? nf + (size_t)row0 * 128 + gk : aggr + (size_t)row0 * 128 + gk - 128;
        const float* p1 = (kc < 4) ? nf + (size_t)row1 * 128 + gk : aggr + (size_t)row1 * 128 + gk - 128;
        const short8 a0 = cvt8(*(const float4*)p0, *(const float4*)(p0 + 4));
        const short8 a1 = cvt8(*(const float4*)p1, *(const float4*)(p1 + 4));
        short8 bfv[8];
        #pragma unroll
        for (int t = 0; t < 8; ++t)
            bfv[t] = *(const short8*)(w1 + (size_t)(t * 16 + le) * 256 + gk);
        #pragma unroll
        for (int t = 0; t < 8; ++t) {
            acc[0][t] = __builtin_amdgcn_mfma_f32_16x16x32_bf16(a0, bfv[t], acc[0][t], 0, 0, 0);
            acc[1][t] = __builtin_amdgcn_mfma_f32_16x16x32_bf16(a1, bfv[t], acc[1][t], 0, 0, 0);
        }
    }
    #pragma unroll
    for (int t = 0; t < 8; ++t) {
        const float b1 = bn1[t * 16 + le];
        #pragma unroll
        for (int m = 0; m < 2; ++m)
            #pragma unroll
            for (int r = 0; r < 4; ++r)
                Hs[wbase + m * 16 + grp * 4 + r][t * 16 + le] = f2bf(silu_f(acc[m][t][r] + b1));
    }

    f32x4 acc2[2][8];
    #pragma unroll
    for (int m = 0; m < 2; ++m)
        #pragma unroll
        for (int t = 0; t < 8; ++t) acc2[m][t] = (f32x4){0.f, 0.f, 0.f, 0.f};

    const short* w2 = wb + OFF_WN2T;
    #pragma unroll
    for (int kc = 0; kc < 4; ++kc) {
        const int gk = kc * 32 + grp * 8;
        const short8 a0 = *(const short8*)&Hs[wbase + le][gk];
        const short8 a1 = *(const short8*)&Hs[wbase + 16 + le][gk];
        short8 bfv[8];
        #pragma unroll
        for (int t = 0; t < 8; ++t)
            bfv[t] = *(const short8*)(w2 + (size_t)(t * 16 + le) * 128 + gk);
        #pragma unroll
        for (int t = 0; t < 8; ++t) {
            acc2[0][t] = __builtin_amdgcn_mfma_f32_16x16x32_bf16(a0, bfv[t], acc2[0][t], 0, 0, 0);
            acc2[1][t] = __builtin_amdgcn_mfma_f32_16x16x32_bf16(a1, bfv[t], acc2[1][t], 0, 0, 0);
        }
    }
    #pragma unroll
    for (int t = 0; t < 8; ++t) {
        const float b2 = bn2[t * 16 + le];
        #pragma unroll
        for (int m = 0; m < 2; ++m)
            #pragma unroll
            for (int r = 0; r < 4; ++r) {
                const int row = nb + wbase + m * 16 + grp * 4 + r;
                if (row < NN) {
                    const int c = t * 16 + le;
                    out[(size_t)row * 128 + c] = acc2[m][t][r] + b2 + nf[(size_t)row * 128 + c];
                }
            }
    }

    for (int i = tid; i < 384; i += 256) {
        const int n = nb + i / 3, j = i % 3;
        if (n < NN)
            out[(size_t)NN * 128 + 3 * n + j] = coords[3 * n + j] + coord_acc[3 * n + j];
    }
}

extern "C" void kernel_launch(void* const* d_in, const int* in_sizes, int n_in,
                              void* d_out, int out_size, void* d_ws, size_t ws_size,
                              hipStream_t stream)
{
    const float* node_feat  = (const float*)d_in[0];
    const float* edge_attr  = (const float*)d_in[1];
    const float* coords     = (const float*)d_in[2];
    const int*   edge_index = (const int*)d_in[3];
    const float* We1 = (const float*)d_in[4];
    const float* be1 = (const float*)d_in[5];
    const float* We2 = (const float*)d_in[6];
    const float* be2 = (const float*)d_in[7];
    const float* Wn1 = (const float*)d_in[8];
    const float* bn1 = (const float*)d_in[9];
    const float* Wn2 = (const float*)d_in[10];
    const float* bn2 = (const float*)d_in[11];
    const float* Wc1 = (const float*)d_in[12];
    const float* bc1 = (const float*)d_in[13];
    const float* Wc2 = (const float*)d_in[14];
    const float* bc2 = (const float*)d_in[15];
    float* out = (float*)d_out;

    const size_t sz_wb  = (size_t)W_TOTAL * 2;      // 229 KB
    const size_t sz_agg = (size_t)NN * 128 * 4;     // 25.6 MB
    const size_t sz_cac = (size_t)NN * 3 * 4;       // 600 KB
    const size_t sz_cnt = (size_t)NN * 4;           // 200 KB
    const size_t sz_y   = (size_t)NN * 128 * 2;     // 12.8 MB each

    char* p = (char*)d_ws;
    short* wbf       = (short*)p;  p += sz_wb;
    float* aggr      = (float*)p;  p += sz_agg;     // aggr, coord_acc, cnt contiguous
    float* coord_acc = (float*)p;  p += sz_cac;     //   (zeroed inside prep_kernel)
    int*   cnt       = (int*)p;    p += sz_cnt;
    short* ysb       = (short*)p;  p += sz_y;
    short* ydb       = (short*)p;  p += sz_y;
    int*   eoff      = (int*)p;    p += (size_t)NN * 4;
    int*   bsum      = (int*)p;    p += 1024;
    int*   bexcl     = (int*)p;    p += 1024;
    int*   cursor    = (int*)p;    p += (size_t)NN * 4;
    int*   csr       = (int*)p;
    (void)ws_size;

    const int eg = NE / 128;                      // 3125 blocks (4 waves x 32 edges)
    const int ng = (NN + 127) / 128;              // 391
    const int eg256 = (NE + 255) / 256;           // 1563
    const int sg = (NN + 255) / 256;              // 196
    const int pg = (W_TOTAL + NZ4 + 255) / 256;   // prep: weights + zero

    prep_kernel<<<pg, 256, 0, stream>>>(We1, We2, Wn1, Wn2, Wc1, wbf, (float4*)aggr);
    ynode_kernel<<<ng, 256, 0, stream>>>(node_feat, wbf, ysb, ydb);

    hist_kernel<<<eg256, 256, 0, stream>>>(edge_index, cnt);
    scanA_kernel<<<sg, 256, 0, stream>>>(cnt, eoff, bsum);
    scanB_kernel<<<1, 256, 0, stream>>>(bsum, bexcl, sg);
    scanC_kernel<<<sg, 256, 0, stream>>>(eoff, bexcl, cursor);
    fill_kernel<<<eg256, 256, 0, stream>>>(edge_index, cursor, csr);

    edge_kernel<<<eg, 256, 0, stream>>>(
        ysb, ydb, edge_attr, coords, edge_index, csr, wbf,
        be1, be2, bc1, bc2, Wc2, aggr, coord_acc);

    node_kernel<<<ng, 256, 0, stream>>>(
        node_feat, coords, wbf, bn1, bn2, aggr, coord_acc, out);
}